// Round 8
// baseline (85.046 us; speedup 1.0000x reference)
//
#include <hip/hip_runtime.h>
#include <math.h>

// GaussianVisibility: R rays x B=24 bones x G=4 gaussians -> shadow map (R,)
// Memory-bound: w2ls (R,24,4,4) fp32 = 100.7 MB. HBM roofline ~16.3us.
//
// R8 = DIAGNOSTIC round. Seven schedule variants (R1-R7) all pinned at
// 26.8-32us with zero counter visibility (kernel never makes rocprof top-5;
// the 56us poison fills outrank it). This round: identical R4 kernel wrapped
// in an nrep=5 internal repeat with per-pass laundered load base (asm "+v",
// defeats cross-pass load CSE) and per-pass keepalive (prevents DCE of
// passes 1-4; rule #17). Output written on last pass only -> identical
// result. Total ~57-130us -> kernel ENTERS top-5; marginal cost per pass
// (L3-served, 100MB < 256MB L3) discriminates HBM-ceiling vs VALU-bound vs
// no-overlap, and FETCH_SIZE/VALUBusy/OccupancyPercent become visible.
//
// Layout (R4, best at 26.8us): 8 lanes/ray, oct=(half,sub); lane owns matrix
// row sub, gaussian g=sub, bones 2k+half. o/n rows shared via DPP quad_perm;
// halves merged with __shfl_xor(4). Per-(b,g) params in LDS, once per block.

#define NB 24
#define NG 4
#define BASE_SCALE 0.001f

template <int CTRL>
__device__ __forceinline__ float dpp_f(float x) {
    int r = __builtin_amdgcn_update_dpp(0, __float_as_int(x), CTRL, 0xF, 0xF, true);
    return __int_as_float(r);
}

__device__ __forceinline__ float frcp(float x) { return __builtin_amdgcn_rcpf(x); }

__global__ __launch_bounds__(256, 8) void gauss_vis_kernel(
    const float* __restrict__ w2ls,
    const float* __restrict__ rays_o,
    const float* __restrict__ rays_d,
    const float* __restrict__ Gs,
    float* __restrict__ out,
    int R, int nrep)
{
    __shared__ float4 P[NB * NG * 3];  // per (b,g): {s00,s01,s02,s11},{s12,s22,mu0,mu1},{mu2,c,-,-}

    const int tid = threadIdx.x;
    const int gid = blockIdx.x * 256 + tid;
    const int ray0 = gid >> 3;
    const int ray = ray0 < R ? ray0 : (R - 1);
    const int oct = tid & 7;   // lane within the ray-octet
    const int sub = oct & 3;   // matrix row + gaussian index
    const int half = oct >> 2; // bone parity

    // ---- per-block param precompute (ray-independent) ----
    if (tid < NB * NG) {
        const float* gp = Gs + tid * 13;
        float mu0 = gp[0], mu1 = gp[1], mu2 = gp[2];
        float s0 = fabsf(gp[3]) + BASE_SCALE;
        float s1 = fabsf(gp[4]) + BASE_SCALE;
        float s2 = fabsf(gp[5]) + BASE_SCALE;
        float ax = gp[6], ay = gp[7], az = gp[8];
        float bx = gp[9], by = gp[10], bz = gp[11];
        float c = fabsf(gp[12]);
        float inv1 = 1.0f / sqrtf(ax * ax + ay * ay + az * az);
        float b1x = ax * inv1, b1y = ay * inv1, b1z = az * inv1;
        float dot = b1x * bx + b1y * by + b1z * bz;
        float t2x = bx - dot * b1x, t2y = by - dot * b1y, t2z = bz - dot * b1z;
        float inv2 = 1.0f / sqrtf(t2x * t2x + t2y * t2y + t2z * t2z);
        float b2x = t2x * inv2, b2y = t2y * inv2, b2z = t2z * inv2;
        float b3x = b1y * b2z - b1z * b2y;
        float b3y = b1z * b2x - b1x * b2z;
        float b3z = b1x * b2y - b1y * b2x;
        float w0 = 1.0f / (s0 * s0), w1 = 1.0f / (s1 * s1), w2 = 1.0f / (s2 * s2);
        float s00 = b1x * b1x * w0 + b1y * b1y * w1 + b1z * b1z * w2;
        float s01 = b1x * b2x * w0 + b1y * b2y * w1 + b1z * b2z * w2;
        float s02 = b1x * b3x * w0 + b1y * b3y * w1 + b1z * b3z * w2;
        float s11 = b2x * b2x * w0 + b2y * b2y * w1 + b2z * b2z * w2;
        float s12 = b2x * b3x * w0 + b2y * b3y * w1 + b2z * b3z * w2;
        float s22 = b3x * b3x * w0 + b3y * b3y * w1 + b3z * b3z * w2;
        P[tid * 3 + 0] = make_float4(s00, s01, s02, s11);
        P[tid * 3 + 1] = make_float4(s12, s22, mu0, mu1);
        P[tid * 3 + 2] = make_float4(mu2, c, 0.f, 0.f);
    }
    __syncthreads();

    const float rox = rays_o[ray * 3 + 0];
    const float roy = rays_o[ray * 3 + 1];
    const float roz = rays_o[ray * 3 + 2];
    const float rdx = rays_d[ray * 3 + 0];
    const float rdy = rays_d[ray * 3 + 1];
    const float rdz = rays_d[ray * 3 + 2];

    const int pi0 = (half * NG + sub) * 3;  // P index for bone `half`, +24 per k
    const float4* __restrict__ Wv = (const float4*)w2ls;

    float sum = 0.f;
#pragma unroll 1
    for (int rep = 0; rep < nrep; ++rep) {
        // launder the base pointer: compiler cannot CSE loads across passes
        unsigned long long wp64 =
            (unsigned long long)(Wv + ((size_t)ray * (NB * 4) + half * 4 + sub));
        asm volatile("" : "+v"(wp64));
        const float4* __restrict__ Wp = (const float4*)wp64;

        float4 M[12];
#pragma unroll
        for (int k = 0; k < 12; ++k) M[k] = Wp[k * 8];

        float s = 0.f;
#pragma unroll
        for (int k = 0; k < 12; ++k) {
            const float4 Mk = M[k];
            float o_s = Mk.x * rox + Mk.y * roy + Mk.z * roz + Mk.w;  // origins homog = 1
            float n_s = Mk.x * rdx + Mk.y * rdy + Mk.z * rdz;         // dirs homog = 0
            float o0 = dpp_f<0x00>(o_s), o1 = dpp_f<0x55>(o_s), o2 = dpp_f<0xAA>(o_s);
            float n0 = dpp_f<0x00>(n_s), n1 = dpp_f<0x55>(n_s), n2 = dpp_f<0xAA>(n_s);

            int pi = pi0 + k * 24;
            float4 p0 = P[pi + 0];
            float4 p1 = P[pi + 1];
            float4 p2 = P[pi + 2];
            float s00 = p0.x, s01 = p0.y, s02 = p0.z, s11 = p0.w;
            float s12 = p1.x, s22 = p1.y;
            float d0 = p1.z - o0, d1 = p1.w - o1, d2 = p2.x - o2;  // mu - o
            float c = p2.y;

            float v0 = s00 * n0 + s01 * n1 + s02 * n2;
            float v1 = s01 * n0 + s11 * n1 + s12 * n2;
            float v2 = s02 * n0 + s12 * n1 + s22 * n2;
            float nSn = v0 * n0 + v1 * n1 + v2 * n2;   // n^T S n
            float nSd = v0 * d0 + v1 * d1 + v2 * d2;   // n^T S (mu-o)
            float q0 = s00 * d0 + s01 * d1 + s02 * d2;
            float q1 = s01 * d0 + s11 * d1 + s12 * d2;
            float q2 = s02 * d0 + s12 * d1 + s22 * d2;
            float quad = q0 * d0 + q1 * d1 + q2 * d2;  // d^T S d

            float rn = frcp(nSn);                 // sigma_bar_sqr
            float mean = nSd * rn;                // mu_bar
            float expo = -0.5f * (quad - nSd * nSd * rn);
            float dens = c * __expf(expo);
            float wsig = frcp(1.f + __expf(1.f - 100.f * mean));  // sigmoid(100*mean-1)
            float arg = (10.f - mean) * __builtin_amdgcn_sqrtf(nSn * 0.5f);
            float sgn = arg > 0.f ? 1.f : -1.f;
            float xa = fabsf(arg);
            float t = frcp(1.f + 0.3275911f * xa);
            float poly = ((((1.061405429f * t - 1.453152027f) * t + 1.421413741f) * t
                           - 0.284496736f) * t + 0.254829592f) * t;
            float erf = sgn * (1.f - poly * __expf(-xa * xa));

            s += dens * wsig * 0.5f * (1.f + erf);
        }
        sum = s;
        asm volatile("" :: "v"(sum));  // keep each pass's result live (no DCE)
    }

    // reduce: quad butterfly (DPP), then merge the two quads of the octet
    sum += dpp_f<0xB1>(sum);       // quad_perm(1,0,3,2)
    sum += dpp_f<0x4E>(sum);       // quad_perm(2,3,0,1)
    sum += __shfl_xor(sum, 4, 64); // half <-> half
    if (oct == 0 && ray0 < R) out[ray0] = __expf(-sum);
}

extern "C" void kernel_launch(void* const* d_in, const int* in_sizes, int n_in,
                              void* d_out, int out_size, void* d_ws, size_t ws_size,
                              hipStream_t stream) {
    const float* w2ls   = (const float*)d_in[0];
    const float* rays_o = (const float*)d_in[1];
    const float* rays_d = (const float*)d_in[2];
    const float* Gs     = (const float*)d_in[3];
    float* out = (float*)d_out;

    const int R = in_sizes[1] / 3;
    const int threads = 256;
    const long long total = (long long)R * 8;
    const int blocks = (int)((total + threads - 1) / threads);
    const int nrep = 5;  // DIAGNOSTIC: x5 repeat to surface kernel in rocprof top-5
    gauss_vis_kernel<<<blocks, threads, 0, stream>>>(w2ls, rays_o, rays_d, Gs, out, R, nrep);
}

// Round 9
// 24.072 us; speedup vs baseline: 3.5329x; 3.5329x over previous
//
#include <hip/hip_runtime.h>
#include <math.h>

// GaussianVisibility: R rays x B=24 bones x G=4 gaussians -> shadow map (R,)
// w2ls (R,24,4,4) fp32 = 100.7 MB stream. HBM floor ~16.3us @6.3TB/s.
//
// R8 diagnostic (nrep=5, counters finally visible): VALUBusy~68%, marginal
// L3-served pass = 14.6us -> VALU issue ~10us, and single-pass 26.8 ==
// serial(16.3 mem + ~10 VALU). Seven schedule variants couldn't create
// overlap; the counter-backed lever is shrinking VALU.
//
// R9 change vs R4 (26.8us): instruction diet on the per-gaussian tail.
//  - A&S erf block (abs/sign-select/5-term poly/rcp/sqrt, ~22 instr) ->
//    cubic-logistic normal CDF (Bowling): Phi(z)=1/(1+exp(-z(1.5976
//    +0.070566 z^2))), z=(10-mean)*nSn*rsqrt(nSn). Odd-symmetric, no sign
//    handling. Max err 1.4e-4/term (headroom: bf16 floor 3.9e-3, thr 2e-2).
//  - v_rsq replaces v_rcp+v_sqrt (rn=r*r), -1 transcendental/iter.
// Est. -19% VALU issue time. Everything else identical to R4.
//
// Layout (R4): 8 lanes/ray, oct=(half,sub); lane owns matrix row sub,
// gaussian g=sub, bones 2k+half. o/n rows shared via DPP quad_perm; halves
// merged with __shfl_xor(4). Per-(b,g) params in LDS, once per block.

#define NB 24
#define NG 4
#define BASE_SCALE 0.001f

template <int CTRL>
__device__ __forceinline__ float dpp_f(float x) {
    int r = __builtin_amdgcn_update_dpp(0, __float_as_int(x), CTRL, 0xF, 0xF, true);
    return __int_as_float(r);
}

__device__ __forceinline__ float frcp(float x) { return __builtin_amdgcn_rcpf(x); }

__global__ __launch_bounds__(256, 8) void gauss_vis_kernel(
    const float* __restrict__ w2ls,
    const float* __restrict__ rays_o,
    const float* __restrict__ rays_d,
    const float* __restrict__ Gs,
    float* __restrict__ out,
    int R)
{
    __shared__ float4 P[NB * NG * 3];  // per (b,g): {s00,s01,s02,s11},{s12,s22,mu0,mu1},{mu2,c,-,-}

    const int tid = threadIdx.x;
    const int gid = blockIdx.x * 256 + tid;
    const int ray0 = gid >> 3;
    const int ray = ray0 < R ? ray0 : (R - 1);
    const int oct = tid & 7;   // lane within the ray-octet
    const int sub = oct & 3;   // matrix row + gaussian index
    const int half = oct >> 2; // bone parity

    // ---- per-block param precompute (ray-independent) ----
    if (tid < NB * NG) {
        const float* gp = Gs + tid * 13;
        float mu0 = gp[0], mu1 = gp[1], mu2 = gp[2];
        float s0 = fabsf(gp[3]) + BASE_SCALE;
        float s1 = fabsf(gp[4]) + BASE_SCALE;
        float s2 = fabsf(gp[5]) + BASE_SCALE;
        float ax = gp[6], ay = gp[7], az = gp[8];
        float bx = gp[9], by = gp[10], bz = gp[11];
        float c = fabsf(gp[12]);
        float inv1 = 1.0f / sqrtf(ax * ax + ay * ay + az * az);
        float b1x = ax * inv1, b1y = ay * inv1, b1z = az * inv1;
        float dot = b1x * bx + b1y * by + b1z * bz;
        float t2x = bx - dot * b1x, t2y = by - dot * b1y, t2z = bz - dot * b1z;
        float inv2 = 1.0f / sqrtf(t2x * t2x + t2y * t2y + t2z * t2z);
        float b2x = t2x * inv2, b2y = t2y * inv2, b2z = t2z * inv2;
        float b3x = b1y * b2z - b1z * b2y;
        float b3y = b1z * b2x - b1x * b2z;
        float b3z = b1x * b2y - b1y * b2x;
        float w0 = 1.0f / (s0 * s0), w1 = 1.0f / (s1 * s1), w2 = 1.0f / (s2 * s2);
        float s00 = b1x * b1x * w0 + b1y * b1y * w1 + b1z * b1z * w2;
        float s01 = b1x * b2x * w0 + b1y * b2y * w1 + b1z * b2z * w2;
        float s02 = b1x * b3x * w0 + b1y * b3y * w1 + b1z * b3z * w2;
        float s11 = b2x * b2x * w0 + b2y * b2y * w1 + b2z * b2z * w2;
        float s12 = b2x * b3x * w0 + b2y * b3y * w1 + b2z * b3z * w2;
        float s22 = b3x * b3x * w0 + b3y * b3y * w1 + b3z * b3z * w2;
        P[tid * 3 + 0] = make_float4(s00, s01, s02, s11);
        P[tid * 3 + 1] = make_float4(s12, s22, mu0, mu1);
        P[tid * 3 + 2] = make_float4(mu2, c, 0.f, 0.f);
    }
    __syncthreads();

    const float rox = rays_o[ray * 3 + 0];
    const float roy = rays_o[ray * 3 + 1];
    const float roz = rays_o[ray * 3 + 2];
    const float rdx = rays_d[ray * 3 + 0];
    const float rdy = rays_d[ray * 3 + 1];
    const float rdz = rays_d[ray * 3 + 2];

    // bone b = 2k + half lives at Wp[k*8] (float4 units); 128B/ray/step,
    // contiguous and 128B-aligned across the octet.
    const float4* __restrict__ Wp =
        (const float4*)w2ls + ((size_t)ray * (NB * 4) + half * 4 + sub);
    const int pi0 = (half * NG + sub) * 3;  // P index for bone `half`, +24 per k

    float sum = 0.f;
#pragma unroll 2
    for (int k = 0; k < 12; ++k) {
        const float4 M = Wp[k * 8];
        float o_s = fmaf(M.x, rox, fmaf(M.y, roy, fmaf(M.z, roz, M.w)));  // homog 1
        float n_s = fmaf(M.x, rdx, fmaf(M.y, rdy, M.z * rdz));            // homog 0
        float o0 = dpp_f<0x00>(o_s), o1 = dpp_f<0x55>(o_s), o2 = dpp_f<0xAA>(o_s);
        float n0 = dpp_f<0x00>(n_s), n1 = dpp_f<0x55>(n_s), n2 = dpp_f<0xAA>(n_s);

        int pi = pi0 + k * 24;
        float4 p0 = P[pi + 0];
        float4 p1 = P[pi + 1];
        float4 p2 = P[pi + 2];
        float s00 = p0.x, s01 = p0.y, s02 = p0.z, s11 = p0.w;
        float s12 = p1.x, s22 = p1.y;
        float d0 = p1.z - o0, d1 = p1.w - o1, d2 = p2.x - o2;  // mu - o
        float c = p2.y;

        float v0 = s00 * n0 + s01 * n1 + s02 * n2;
        float v1 = s01 * n0 + s11 * n1 + s12 * n2;
        float v2 = s02 * n0 + s12 * n1 + s22 * n2;
        float nSn = v0 * n0 + v1 * n1 + v2 * n2;   // n^T S n
        float nSd = v0 * d0 + v1 * d1 + v2 * d2;   // n^T S (mu-o)
        float q0 = s00 * d0 + s01 * d1 + s02 * d2;
        float q1 = s01 * d0 + s11 * d1 + s12 * d2;
        float q2 = s02 * d0 + s12 * d1 + s22 * d2;
        float quad = q0 * d0 + q1 * d1 + q2 * d2;  // d^T S d

        float r = __builtin_amdgcn_rsqf(nSn);  // 1/sigma ... r^2 = sigma_bar_sqr^-1... wait: r = 1/sqrt(nSn)
        float rn = r * r;                      // 1/nSn = sigma_bar_sqr
        float mean = nSd * rn;                 // mu_bar
        float expo = -0.5f * (quad - nSd * nSd * rn);
        float dens = c * __expf(expo);
        float wsig = frcp(1.f + __expf(1.f - 100.f * mean));  // sigmoid(100*mean-1)

        // normal CDF: Phi(z), z = (10-mean)/sigma = (10-mean)*sqrt(nSn) = (10-mean)*nSn*r
        // cubic-logistic approx (max abs err ~1.4e-4), odd-symmetric -> no sign split
        float z = (10.f - mean) * (nSn * r);
        float zz = z * z;
        float a = z * fmaf(0.070565992f, zz, 1.5976f);
        float cdf = frcp(1.f + __expf(-a));

        sum = fmaf(dens * wsig, cdf, sum);
    }

    // reduce: quad butterfly (DPP), then merge the two quads of the octet
    sum += dpp_f<0xB1>(sum);       // quad_perm(1,0,3,2)
    sum += dpp_f<0x4E>(sum);       // quad_perm(2,3,0,1)
    sum += __shfl_xor(sum, 4, 64); // half <-> half
    if (oct == 0 && ray0 < R) out[ray0] = __expf(-sum);
}

extern "C" void kernel_launch(void* const* d_in, const int* in_sizes, int n_in,
                              void* d_out, int out_size, void* d_ws, size_t ws_size,
                              hipStream_t stream) {
    const float* w2ls   = (const float*)d_in[0];
    const float* rays_o = (const float*)d_in[1];
    const float* rays_d = (const float*)d_in[2];
    const float* Gs     = (const float*)d_in[3];
    float* out = (float*)d_out;

    const int R = in_sizes[1] / 3;
    const int threads = 256;
    const long long total = (long long)R * 8;
    const int blocks = (int)((total + threads - 1) / threads);
    gauss_vis_kernel<<<blocks, threads, 0, stream>>>(w2ls, rays_o, rays_d, Gs, out, R);
}